// Round 4
// baseline (350.448 us; speedup 1.0000x reference)
//
#include <hip/hip_runtime.h>
#include <hip/hip_bf16.h>
#include <stdint.h>

#define K_DIM 1024
#define N_DIM 1024
#define BM 128
#define BN 128
#define BK 32

typedef __attribute__((ext_vector_type(8))) short short8;
typedef __attribute__((ext_vector_type(4))) float f32x4;

// ---- async global->LDS, 16B per lane (dest = wave-uniform base + lane*16) ----
__device__ __forceinline__ void gld16(const void* g, void* l) {
    __builtin_amdgcn_global_load_lds(
        (const __attribute__((address_space(1))) uint32_t*)(uintptr_t)g,
        (__attribute__((address_space(3))) uint32_t*)(uint32_t)(uintptr_t)l,
        16, 0, 0);
}

// pack two fp32 -> bf16x2 (round-half-up; |rel err| <= 2^-9)
__device__ __forceinline__ uint32_t pack2(float lo, float hi) {
    uint32_t a = __float_as_uint(lo) + 0x8000u;
    uint32_t b = __float_as_uint(hi) + 0x8000u;
    return __builtin_amdgcn_perm(b, a, 0x07060302u);
}

// XCD-aware swizzle: consecutive linear IDs round-robin XCDs; give each XCD a
// contiguous 32-mb slab so the 8 blocks sharing an A-tile land on ONE XCD's L2.
__device__ __forceinline__ void block_map(int b, int& mb, int& nb) {
    int xcd = b & 7;
    int i = b >> 3;              // 0..255 within XCD
    mb = xcd * 32 + (i >> 3);    // 32 consecutive m-blocks per XCD
    nb = i & 7;
}

// ---- stage 1: per-block |W| partial sums (fp64, deterministic) ----
__global__ void k_abs_partial(const float* __restrict__ W, double* __restrict__ part, int n4) {
    int stride = gridDim.x * blockDim.x;
    double s = 0.0;
    for (int i = blockIdx.x * blockDim.x + threadIdx.x; i < n4; i += stride) {
        float4 v = ((const float4*)W)[i];
        s += (double)fabsf(v.x) + (double)fabsf(v.y) + (double)fabsf(v.z) + (double)fabsf(v.w);
    }
    for (int o = 32; o > 0; o >>= 1) s += __shfl_down(s, o, 64);
    __shared__ double sm[4];
    int lane = threadIdx.x & 63, wv = threadIdx.x >> 6;
    if (lane == 0) sm[wv] = s;
    __syncthreads();
    if (threadIdx.x == 0) part[blockIdx.x] = sm[0] + sm[1] + sm[2] + sm[3];
}

// ---- stage 2: final reduce, store threshold = 0.5*mean(|W|) at ws[0] ----
__global__ void k_abs_final(double* __restrict__ ws) {
    double s = ws[8 + threadIdx.x];
    for (int o = 32; o > 0; o >>= 1) s += __shfl_down(s, o, 64);
    __shared__ double sm[4];
    int lane = threadIdx.x & 63, wv = threadIdx.x >> 6;
    if (lane == 0) sm[wv] = s;
    __syncthreads();
    if (threadIdx.x == 0)
        ws[0] = 0.5 * (sm[0] + sm[1] + sm[2] + sm[3]) / (double)(K_DIM * N_DIM);
}

// ---- stage 3: ternary quantize W -> bf16 {-1,0,+1} ----
__global__ void k_quant(const float* __restrict__ W, const double* __restrict__ thr,
                        ushort* __restrict__ wt, int n4) {
    float t = (float)thr[0];
    int i = blockIdx.x * blockDim.x + threadIdx.x;
    if (i >= n4) return;
    float4 v = ((const float4*)W)[i];
    ushort4 o;
    o.x = v.x > t ? 0x3F80u : (v.x < -t ? 0xBF80u : 0u);
    o.y = v.y > t ? 0x3F80u : (v.y < -t ? 0xBF80u : 0u);
    o.z = v.z > t ? 0x3F80u : (v.z < -t ? 0xBF80u : 0u);
    o.w = v.w > t ? 0x3F80u : (v.w < -t ? 0xBF80u : 0u);
    ((ushort4*)wt)[i] = o;
}

// ---- stage 4: fused GEMM  out[M,N] = bf16(x)[M,K] @ wt[N,K]^T + b ----
// 256 thr = 4 waves (2x2), wave = 64x64 via 4x4 of 16x16x32 bf16 MFMA.
// A: fp32 global -> regs -> pack bf16 -> ds_write (8 KB LDS, [m][k] bf16).
//    Register staging double-buffers A: loads for iter k+1 issue before the
//    compute barrier of iter k (a full MFMA section of latency cover).
// B: ternary bf16 via gld16 (8 KB LDS). XCD-swizzled block mapping.
__global__ __launch_bounds__(256) void k_gemm(
    const float* __restrict__ x, const ushort* __restrict__ wt,
    const float* __restrict__ bias, float* __restrict__ out) {
    __shared__ __align__(16) ushort As[BM * BK];   // 8 KB [m][k]
    __shared__ __align__(16) ushort Bs[BN * BK];   // 8 KB [n][k]

    const int tid  = threadIdx.x;
    const int lane = tid & 63;
    const int wv   = tid >> 6;
    const int wm   = wv >> 1;
    const int wn   = wv & 1;
    const int r    = lane & 15;
    const int quad = lane >> 4;
    int mb, nb;
    block_map(blockIdx.x, mb, nb);
    const int m0 = mb * BM;
    const int n0 = nb * BN;

    // A register staging: wave wv covers rows [wv*32, wv*32+32).
    // Lane: rows srow and srow+16; 8 consecutive fp32 at col (lane&3)*8.
    const int srow = lane >> 2;          // 0..15
    const int scol = (lane & 3) * 8;     // fp32 col offset
    const float* gA = x + (size_t)(m0 + wv * 32 + srow) * K_DIM + scol;
    ushort* lAw = As + (wv * 32 + srow) * BK + scol;   // same layout in bf16

    // B staging via gld16: per issue 16 rows x 4 groups of 8 bf16 (16 B/lane).
    const ushort* gB = wt + (size_t)(n0 + wv * 32 + srow) * K_DIM + (lane & 3) * 8;
    ushort* lB = Bs + (wv * 32) * BK;

    f32x4 acc[4][4];
#pragma unroll
    for (int i = 0; i < 4; i++)
#pragma unroll
        for (int j = 0; j < 4; j++)
            acc[i][j] = (f32x4){0.f, 0.f, 0.f, 0.f};

    // prologue: A regs for iter 0
    float4 a0 = *(const float4*)(gA);
    float4 a1 = *(const float4*)(gA + 4);
    float4 a2 = *(const float4*)(gA + (size_t)16 * K_DIM);
    float4 a3 = *(const float4*)(gA + (size_t)16 * K_DIM + 4);

    for (int k0 = 0; k0 < K_DIM; k0 += BK) {
        // B async into LDS (prev-iter reads already done: barrier at loop end)
#pragma unroll
        for (int i = 0; i < 2; i++)
            gld16(gB + (size_t)(i * 16) * K_DIM + k0, lB + (i * 16) * BK);

        // A: pack current regs -> LDS
        uint4 p0, p1;
        p0.x = pack2(a0.x, a0.y); p0.y = pack2(a0.z, a0.w);
        p0.z = pack2(a1.x, a1.y); p0.w = pack2(a1.z, a1.w);
        p1.x = pack2(a2.x, a2.y); p1.y = pack2(a2.z, a2.w);
        p1.z = pack2(a3.x, a3.y); p1.w = pack2(a3.z, a3.w);
        *(uint4*)(lAw)            = p0;
        *(uint4*)(lAw + 16 * BK)  = p1;

        // A regs for next iter: issued now, consumed after next barrier pair
        if (k0 + BK < K_DIM) {
            const float* g = gA + k0 + BK;
            a0 = *(const float4*)(g);
            a1 = *(const float4*)(g + 4);
            a2 = *(const float4*)(g + (size_t)16 * K_DIM);
            a3 = *(const float4*)(g + (size_t)16 * K_DIM + 4);
        }
        __syncthreads();   // drains gld16 (vmcnt) + ds_write (lgkm)

        short8 a[4], b[4];
#pragma unroll
        for (int mi = 0; mi < 4; mi++)
            a[mi] = *(const short8*)(As + (wm * 64 + mi * 16 + r) * BK + quad * 8);
#pragma unroll
        for (int nj = 0; nj < 4; nj++)
            b[nj] = *(const short8*)(Bs + (wn * 64 + nj * 16 + r) * BK + quad * 8);
#pragma unroll
        for (int mi = 0; mi < 4; mi++)
#pragma unroll
            for (int nj = 0; nj < 4; nj++)
                acc[mi][nj] = __builtin_amdgcn_mfma_f32_16x16x32_bf16(
                    a[mi], b[nj], acc[mi][nj], 0, 0, 0);
        __syncthreads();   // LDS reads done before next iter overwrites
    }

    // epilogue: C/D layout col=lane&15, row=quad*4+reg (m89-verified)
    float bv[4];
#pragma unroll
    for (int nj = 0; nj < 4; nj++) bv[nj] = bias[n0 + wn * 64 + nj * 16 + r];
#pragma unroll
    for (int mi = 0; mi < 4; mi++)
#pragma unroll
        for (int nj = 0; nj < 4; nj++) {
            const int col = n0 + wn * 64 + nj * 16 + r;
#pragma unroll
            for (int i = 0; i < 4; i++) {
                const int row = m0 + wm * 64 + mi * 16 + quad * 4 + i;
                out[(size_t)row * N_DIM + col] = acc[mi][nj][i] + bv[nj];
            }
        }
}

extern "C" void kernel_launch(void* const* d_in, const int* in_sizes, int n_in,
                              void* d_out, int out_size, void* d_ws, size_t ws_size,
                              hipStream_t stream) {
    const float* x = (const float*)d_in[0];
    const float* W = (const float*)d_in[1];
    const float* b = (const float*)d_in[2];
    float* out = (float*)d_out;
    double* wsd = (double*)d_ws;                       // ws[0]=thr, ws[8..263]=partials
    ushort* wt = (ushort*)((char*)d_ws + 4096);        // 2 MB ternary bf16 [O,K]
    const int M = in_sizes[0] / K_DIM;                 // 32768

    const int n4 = (K_DIM * N_DIM) / 4;
    k_abs_partial<<<256, 256, 0, stream>>>(W, wsd + 8, n4);
    k_abs_final<<<1, 256, 0, stream>>>(wsd);
    k_quant<<<n4 / 256, 256, 0, stream>>>(W, wsd, wt, n4);

    const int nblocks = (M / BM) * (N_DIM / BN);       // 2048
    k_gemm<<<nblocks, 256, 0, stream>>>(x, wt, b, out);
}